// Round 25
// baseline (86.250 us; speedup 1.0000x reference)
//
#include <hip/hip_runtime.h>
#include <hip/hip_bf16.h>
#include <math.h>

#define BB 4
#define TT 4096
#define DD 512
#define HH 64
#define TW 128   // TT/32 words

typedef unsigned int u32;
typedef unsigned short u16;
typedef float f32x16 __attribute__((ext_vector_type(16)));
typedef __bf16 bf16x8 __attribute__((ext_vector_type(8)));

#define SC 0.18033688011112042f  /* 0.125 * log2(e), folded into Q at proj */

static __device__ __forceinline__ u16 f2b(float f) {
    __hip_bfloat16 h = __float2bfloat16(f);
    return __builtin_bit_cast(u16, h);
}
static __device__ __forceinline__ float b2f(u16 x) {
    return __builtin_bit_cast(float, (u32)x << 16);
}
static __device__ __forceinline__ u32 pk2(float a, float b) {
    return (u32)f2b(a) | ((u32)f2b(b) << 16);
}
static __device__ __forceinline__ bf16x8 ldf(const u16* p) {
    uint4 u = *(const uint4*)p;
    return __builtin_bit_cast(bf16x8, u);
}
static __device__ __forceinline__ bf16x8 ldsf(const u16* p) {
    uint4 u = *(const uint4*)p;
    return __builtin_bit_cast(bf16x8, u);
}
// swap high 32 lanes of a with low 32 lanes of b (both results used)
static __device__ __forceinline__ void swap32(u32& a, u32& b) {
    asm("v_permlane32_swap_b32 %0, %1" : "+v"(a), "+v"(b));
}
static __device__ __forceinline__ u32 bits8(int4 a0, int4 a1, int4 a2, int4 a3,
                                            int4 a4, int4 a5, int4 a6, int4 a7) {
    u32 mk = 0;
    mk |= (a0.x != 0 ? 1u : 0u) << 0;  mk |= (a0.y != 0 ? 1u : 0u) << 1;
    mk |= (a0.z != 0 ? 1u : 0u) << 2;  mk |= (a0.w != 0 ? 1u : 0u) << 3;
    mk |= (a1.x != 0 ? 1u : 0u) << 4;  mk |= (a1.y != 0 ? 1u : 0u) << 5;
    mk |= (a1.z != 0 ? 1u : 0u) << 6;  mk |= (a1.w != 0 ? 1u : 0u) << 7;
    mk |= (a2.x != 0 ? 1u : 0u) << 8;  mk |= (a2.y != 0 ? 1u : 0u) << 9;
    mk |= (a2.z != 0 ? 1u : 0u) << 10; mk |= (a2.w != 0 ? 1u : 0u) << 11;
    mk |= (a3.x != 0 ? 1u : 0u) << 12; mk |= (a3.y != 0 ? 1u : 0u) << 13;
    mk |= (a3.z != 0 ? 1u : 0u) << 14; mk |= (a3.w != 0 ? 1u : 0u) << 15;
    mk |= (a4.x != 0 ? 1u : 0u) << 16; mk |= (a4.y != 0 ? 1u : 0u) << 17;
    mk |= (a4.z != 0 ? 1u : 0u) << 18; mk |= (a4.w != 0 ? 1u : 0u) << 19;
    mk |= (a5.x != 0 ? 1u : 0u) << 20; mk |= (a5.y != 0 ? 1u : 0u) << 21;
    mk |= (a5.z != 0 ? 1u : 0u) << 22; mk |= (a5.w != 0 ? 1u : 0u) << 23;
    mk |= (a6.x != 0 ? 1u : 0u) << 24; mk |= (a6.y != 0 ? 1u : 0u) << 25;
    mk |= (a6.z != 0 ? 1u : 0u) << 26; mk |= (a6.w != 0 ? 1u : 0u) << 27;
    mk |= (a7.x != 0 ? 1u : 0u) << 28; mk |= (a7.y != 0 ? 1u : 0u) << 29;
    mk |= (a7.z != 0 ? 1u : 0u) << 30; mk |= (a7.w != 0 ? 1u : 0u) << 31;
    return mk;
}

// Fragment-order layouts (MFMA 32x32x16 fragment: lane&31 = row/col-of-32,
// lane>>5 = k-half, 8 consecutive k per lane):
//   QF/KF: [b*128 + tile][kt=0..3][lane][8 u16]  (row = t, k = d); QF pre-scaled
//   VF:    [b*128 + tile][hg*2+k2][lane][8 u16]  (col = h, k = i-local); VF2 = scaled
//   WF:    [m][kt=0..31][nt][lane][8 u16]        (col = n, k = d)  B-frag
//   bits2:  [jt][i]  word = 32 j-bits for row i
//   bitsTT: [it][j]  word = 32 i-bits for col j
//
// r25: same 4-launch pipeline as r24, but ppF's pack path is a grid-stride
// loop with TWO half-row units in flight per iteration (16 independent int4
// loads; counted vmcnt keeps unit-1 loads in flight during unit-0 compute) --
// the m13 copy pattern. r24's pack gave each wave ONE 8-load shot -> one
// latency generation per 8 KB -> 1.58 TB/s cap.
// XCD pinning (stats/out): b = (bid&7)>>1 -> batch b owns XCD pair {2b,2b+1}.

// ---------------------------------------------------------------------------
// wtr: fp32 W[512][64] x3 -> bf16 WF B-fragment order. 24 blocks.
// ---------------------------------------------------------------------------
__global__ __launch_bounds__(256) void wtr_kernel(const float* __restrict__ Wq,
                                                  const float* __restrict__ Wk,
                                                  const float* __restrict__ Wv,
                                                  u16* __restrict__ WF) {
    const int wb = blockIdx.x;            // 0..23
    const int m = wb >> 3, sub = wb & 7;
    const float* W = (m == 0) ? Wq : (m == 1) ? Wk : Wv;
    const int t = threadIdx.x;
    const int n = sub * 8 + (t >> 5);     // 0..63
    const int kt = t & 31;
    const int l31 = n & 31, nt = n >> 5;
#pragma unroll
    for (int kk = 0; kk < 16; ++kk) {
        const int hf = kk >> 3, e = kk & 7;
        WF[(size_t)m * 32768 + kt * 1024 + nt * 512 + (hf * 32 + l31) * 8 + e]
            = f2b(W[(size_t)(kt * 16 + kk) * HH + n]);
    }
}

// ---------------------------------------------------------------------------
// ppF: heterogeneous launch. Blocks 0..511 = projF (LDS-fused X-convert +
// QKV MFMA, 384 thr); blocks 512..853 = grid-stride dag pack (2-way ILP).
// ---------------------------------------------------------------------------
__global__ __launch_bounds__(384) void ppF_kernel(const float* __restrict__ X,
                                                  const u16* __restrict__ WF,
                                                  u16* __restrict__ QF,
                                                  u16* __restrict__ KF,
                                                  u16* __restrict__ VF,
                                                  const int* __restrict__ dag,
                                                  u32* __restrict__ bits2) {
    __shared__ u16 XS[16384];          // 32 KB, A-frag order [kt][lane][8]
    if (blockIdx.x >= 512) {
        // ---- pack path: grid-stride, 2 units (16 int4 loads) in flight ----
        const int w = threadIdx.x >> 6, lane = threadIdx.x & 63;
        const int stride = 342 * 6;                     // 2052 waves
        int u0 = (blockIdx.x - 512) * 6 + w;
        const int lo = lane * 32;
        while (u0 < 8192) {
            const int u1 = u0 + stride;
            const bool has1 = (u1 < 8192);
            const int r0 = u0 >> 1, h0 = u0 & 1;
            const int u1s = has1 ? u1 : u0;
            const int r1 = u1s >> 1, h1 = u1s & 1;
            const int4* p0 = (const int4*)(dag + (size_t)r0 * TT + h0 * 2048 + lo);
            const int4* p1 = (const int4*)(dag + (size_t)r1 * TT + h1 * 2048 + lo);
            int4 a0 = p0[0], a1 = p0[1], a2 = p0[2], a3 = p0[3];
            int4 a4 = p0[4], a5 = p0[5], a6 = p0[6], a7 = p0[7];
            int4 b0 = p1[0], b1 = p1[1], b2 = p1[2], b3 = p1[3];
            int4 b4 = p1[4], b5 = p1[5], b6 = p1[6], b7 = p1[7];
            u32 mk0 = bits8(a0, a1, a2, a3, a4, a5, a6, a7);
            bits2[(size_t)(h0 * 64 + lane) * TT + r0] = mk0;
            u32 mk1 = bits8(b0, b1, b2, b3, b4, b5, b6, b7);
            if (has1) bits2[(size_t)(h1 * 64 + lane) * TT + r1] = mk1;
            u0 += 2 * stride;
        }
        return;
    }
    // ---- projF path ----
    const int tile = blockIdx.x;
    const int t = threadIdx.x;
    // phase 1: stage X tile (32 rows x 512 cols fp32) -> bf16 A-frag LDS
    for (int g = t; g < 4096; g += 384) {
        const int rl = g >> 7, c4 = g & 127;
        const int d0 = c4 * 4;
        const int kt = d0 >> 4, hf = (d0 >> 3) & 1, e0 = d0 & 7;
        float4 v = *(const float4*)(X + ((size_t)tile * 32 + rl) * DD + d0);
        u32* dst = (u32*)&XS[kt * 512 + (hf * 32 + rl) * 8 + e0];
        dst[0] = pk2(v.x, v.y);
        dst[1] = pk2(v.z, v.w);
    }
    __syncthreads();
    // phase 2: MFMA
    const int w = t >> 6, lane = t & 63;
    const int m = w >> 1, nt = w & 1;
    const int l31 = lane & 31, hf = lane >> 5;
    const u16* xs = XS + lane * 8;
    const u16* wf = WF + (size_t)m * 32768 + nt * 512 + lane * 8;

    f32x16 acc = {};
#pragma unroll 8
    for (int kt = 0; kt < 32; ++kt) {
        bf16x8 xa = ldsf(xs + kt * 512);
        acc = __builtin_amdgcn_mfma_f32_32x32x16_bf16(xa, ldf(wf + kt * 1024), acc, 0, 0, 0);
    }
    const float sc = (m == 0) ? SC : 1.0f;
    if (m < 2) {
        // A-fragment order: row = tile*32+rl, n = nt*32+l31
        u16* dst = (m == 0) ? QF : KF;
        const int kth = l31 >> 4, hfp = (l31 >> 3) & 1, e = l31 & 7;
#pragma unroll
        for (int r = 0; r < 16; ++r) {
            int rl = (r & 3) + 8 * (r >> 2) + 4 * hf;
            dst[(size_t)tile * 2048 + (nt * 2 + kth) * 512 + (rl + hfp * 32) * 8 + e]
                = f2b(acc[r] * sc);
        }
    } else {
        // B-fragment order: col = h = nt*32+l31, k = i-local = rl
#pragma unroll
        for (int r = 0; r < 16; ++r) {
            int rl = (r & 3) + 8 * (r >> 2) + 4 * hf;
            VF[(size_t)tile * 2048 + (nt * 2 + (rl >> 4)) * 512
               + (l31 + ((rl >> 3) & 1) * 32) * 8 + (rl & 7)] = f2b(acc[r]);
        }
    }
}

// ---------------------------------------------------------------------------
// transtats: heterogeneous launch of two INDEPENDENT jobs.
// Blocks 0..255   = stats (+V-scale) path, 512 thr, XCD-pinned.
// Blocks 256..1279 = bit-transpose path (8 waves x 2 tiles each).
// ---------------------------------------------------------------------------
__global__ __launch_bounds__(512, 2) void transtats_kernel(const u16* __restrict__ QF,
                                                           const u16* __restrict__ KF,
                                                           const u32* __restrict__ bits2,
                                                           const u16* __restrict__ VF,
                                                           u16* __restrict__ VF2,
                                                           u32* __restrict__ bitsTT) {
    __shared__ float Lsh[8][128];
    __shared__ float cSh[64];
    if (blockIdx.x >= 256) {
        // ---------------- trans path ----------------
        const int w = threadIdx.x >> 6, lane = threadIdx.x & 63;
        const int l31 = lane & 31, grp = lane >> 5;
        const int g = (blockIdx.x - 256) * 16 + w * 2 + grp;   // 0..16383
        const int it = g >> 7, jt = g & 127;
        u32 S = bits2[(size_t)jt * TT + it * 32 + l31];
        u32 sel = 0;
        const bool low = (lane < 32);
#pragma unroll
        for (int jb = 0; jb < 32; ++jb) {
            unsigned long long m = __ballot((S >> jb) & 1);
            u32 pick = low ? (u32)m : (u32)(m >> 32);
            sel = (l31 == jb) ? pick : sel;
        }
        bitsTT[(size_t)it * TT + jt * 32 + l31] = sel;
        return;
    }
    // ---------------- stats path ----------------
    const int bid = blockIdx.x;
    const int b = (bid & 7) >> 1;
    const int u = (bid & 1) * 32 + (bid >> 3);
    const int itg0 = u * 2;
    const int i0 = itg0 * 32;
    const int w = threadIdx.x >> 6, lane = threadIdx.x & 63;
    const int l31 = lane & 31, hf = lane >> 5;

    bf16x8 qfA[4], qfB[4];
    const u16* qbase = QF + (size_t)(b * 128 + itg0) * 2048 + lane * 8;
#pragma unroll
    for (int kt = 0; kt < 4; ++kt) {
        qfA[kt] = ldf(qbase + kt * 512);
        qfB[kt] = ldf(qbase + 2048 + kt * 512);
    }

    const u16* kf0 = KF + (size_t)b * 128 * 2048 + lane * 8;

    float LpA = 0.f, LpB = 0.f;
    for (int t = 0; t < 16; ++t) {
        const int jt = w + t * 8;
        const u16* kb = kf0 + (size_t)jt * 2048;
        u32 mwA = bits2[(size_t)jt * TT + i0 + l31];
        u32 mwB = bits2[(size_t)jt * TT + i0 + 32 + l31];

        bf16x8 k0 = ldf(kb), k1 = ldf(kb + 512), k2 = ldf(kb + 1024), k3 = ldf(kb + 1536);
        __builtin_amdgcn_s_setprio(1);
        f32x16 sA = {}, sB = {};
        sA = __builtin_amdgcn_mfma_f32_32x32x16_bf16(k0, qfA[0], sA, 0, 0, 0);
        sB = __builtin_amdgcn_mfma_f32_32x32x16_bf16(k0, qfB[0], sB, 0, 0, 0);
        sA = __builtin_amdgcn_mfma_f32_32x32x16_bf16(k1, qfA[1], sA, 0, 0, 0);
        sB = __builtin_amdgcn_mfma_f32_32x32x16_bf16(k1, qfB[1], sB, 0, 0, 0);
        sA = __builtin_amdgcn_mfma_f32_32x32x16_bf16(k2, qfA[2], sA, 0, 0, 0);
        sB = __builtin_amdgcn_mfma_f32_32x32x16_bf16(k2, qfB[2], sB, 0, 0, 0);
        sA = __builtin_amdgcn_mfma_f32_32x32x16_bf16(k3, qfA[3], sA, 0, 0, 0);
        sB = __builtin_amdgcn_mfma_f32_32x32x16_bf16(k3, qfB[3], sB, 0, 0, 0);
        __builtin_amdgcn_s_setprio(0);
        u32 mrA = __builtin_amdgcn_alignbit(mwA, mwA, hf * 4);  // rotr by 4*hf
        u32 mrB = __builtin_amdgcn_alignbit(mwB, mwB, hf * 4);
#pragma unroll
        for (int r = 0; r < 16; ++r) {
            const int pos = (r & 3) + 8 * (r >> 2);
            float eA = __builtin_amdgcn_exp2f(sA[r]);
            float eB = __builtin_amdgcn_exp2f(sB[r]);
            LpA += ((mrA >> pos) & 1) ? eA : 0.f;
            LpB += ((mrB >> pos) & 1) ? eB : 0.f;
        }
    }
    Lsh[w][lane] = LpA;
    Lsh[w][64 + lane] = LpB;
    __syncthreads();
    if (threadIdx.x < 64) {
        const int g = threadIdx.x >> 5, il = threadIdx.x & 31;
        float L = 0.f;
#pragma unroll
        for (int q = 0; q < 8; ++q) L += Lsh[q][g * 64 + il] + Lsh[q][g * 64 + il + 32];
        cSh[g * 32 + il] = (L > 0.f) ? 1.f / L : 0.f;
    }
    __syncthreads();
    // scale the block's two VF tiles (512 uint4) into VF2; 1 uint4/thread
    {
        const int tl = threadIdx.x >> 8;          // 0..1 tile-local
        const int rem = threadIdx.x & 255;
        const int q = rem >> 6, ln = rem & 63;
        const int ib = tl * 32 + (q & 1) * 16 + (ln >> 5) * 8;
        float4 c0 = *(const float4*)&cSh[ib];
        float4 c1 = *(const float4*)&cSh[ib + 4];
        const size_t off = (size_t)(b * 128 + itg0 + tl) * 2048 + q * 512 + ln * 8;
        uint4 v = *(const uint4*)(VF + off);
        u16* ve = (u16*)&v;
        ve[0] = f2b(b2f(ve[0]) * c0.x);
        ve[1] = f2b(b2f(ve[1]) * c0.y);
        ve[2] = f2b(b2f(ve[2]) * c0.z);
        ve[3] = f2b(b2f(ve[3]) * c0.w);
        ve[4] = f2b(b2f(ve[4]) * c1.x);
        ve[5] = f2b(b2f(ve[5]) * c1.y);
        ve[6] = f2b(b2f(ve[6]) * c1.z);
        ve[7] = f2b(b2f(ve[7]) * c1.w);
        *(uint4*)(VF2 + off) = v;
    }
}

// ---------------------------------------------------------------------------
// Output: TWO adjacent 32-j tiles per block; each Q/V load feeds both S/PV
// chains. Block 512 thr (8 waves), 8-way i-split. Grid 256. XCD-pinned.
// ---------------------------------------------------------------------------
__global__ __launch_bounds__(512, 2) void out_kernel(const u16* __restrict__ QF,
                                                     const u16* __restrict__ KF,
                                                     const u16* __restrict__ VF2,
                                                     const u32* __restrict__ bitsTT,
                                                     float* __restrict__ out) {
    __shared__ float red[2][4][2048];
    const int bid = blockIdx.x;
    const int b = (bid & 7) >> 1;
    const int u = (bid & 1) * 32 + (bid >> 3);
    const int jt0 = u * 2;
    const int j0 = jt0 * 32;
    const int w = threadIdx.x >> 6, lane = threadIdx.x & 63;
    const int l31 = lane & 31, hf = lane >> 5;

    bf16x8 kfA[4], kfB[4];
    const u16* kbase = KF + (size_t)(b * 128 + jt0) * 2048 + lane * 8;
#pragma unroll
    for (int kt = 0; kt < 4; ++kt) {
        kfA[kt] = ldf(kbase + kt * 512);
        kfB[kt] = ldf(kbase + 2048 + kt * 512);
    }

    const u16* qf0 = QF + (size_t)b * 128 * 2048 + lane * 8;
    const u16* vf0 = VF2 + (size_t)b * 128 * 2048 + lane * 8;

    f32x16 accA0 = {}, accA1 = {}, accB0 = {}, accB1 = {};

    for (int t = 0; t < 16; ++t) {
        const int it = w + t * 8;
        const u16* qb = qf0 + (size_t)it * 2048;
        const u16* vb = vf0 + (size_t)it * 2048;
        u32 mwA = bitsTT[(size_t)it * TT + j0 + l31];
        u32 mwB = bitsTT[(size_t)it * TT + j0 + 32 + l31];

        bf16x8 q0 = ldf(qb), q1 = ldf(qb + 512), q2 = ldf(qb + 1024), q3 = ldf(qb + 1536);
        __builtin_amdgcn_s_setprio(1);
        f32x16 sA = {}, sB = {};
        sA = __builtin_amdgcn_mfma_f32_32x32x16_bf16(q0, kfA[0], sA, 0, 0, 0);
        sB = __builtin_amdgcn_mfma_f32_32x32x16_bf16(q0, kfB[0], sB, 0, 0, 0);
        sA = __builtin_amdgcn_mfma_f32_32x32x16_bf16(q1, kfA[1], sA, 0, 0, 0);
        sB = __builtin_amdgcn_mfma_f32_32x32x16_bf16(q1, kfB[1], sB, 0, 0, 0);
        sA = __builtin_amdgcn_mfma_f32_32x32x16_bf16(q2, kfA[2], sA, 0, 0, 0);
        sB = __builtin_amdgcn_mfma_f32_32x32x16_bf16(q2, kfB[2], sB, 0, 0, 0);
        sA = __builtin_amdgcn_mfma_f32_32x32x16_bf16(q3, kfA[3], sA, 0, 0, 0);
        sB = __builtin_amdgcn_mfma_f32_32x32x16_bf16(q3, kfB[3], sB, 0, 0, 0);
        __builtin_amdgcn_s_setprio(0);

        u32 mrA = __builtin_amdgcn_alignbit(mwA, mwA, hf * 4);  // rotr by 4*hf
        u32 mrB = __builtin_amdgcn_alignbit(mwB, mwB, hf * 4);

        float pA[16], pB[16];
#pragma unroll
        for (int r = 0; r < 16; ++r) {
            const int pos = (r & 3) + 8 * (r >> 2);
            float eA = __builtin_amdgcn_exp2f(sA[r]);
            float eB = __builtin_amdgcn_exp2f(sB[r]);
            pA[r] = ((mrA >> pos) & 1) ? eA : 0.f;
            pB[r] = ((mrB >> pos) & 1) ? eB : 0.f;
        }

        bf16x8 v00 = ldf(vb), v01 = ldf(vb + 512), v10 = ldf(vb + 1024), v11 = ldf(vb + 1536);

#pragma unroll
        for (int k2 = 0; k2 < 2; ++k2) {
            u32 aA  = pk2(pA[8 * k2 + 0], pA[8 * k2 + 1]);
            u32 bA  = pk2(pA[8 * k2 + 2], pA[8 * k2 + 3]);
            u32 cA  = pk2(pA[8 * k2 + 4], pA[8 * k2 + 5]);
            u32 dA  = pk2(pA[8 * k2 + 6], pA[8 * k2 + 7]);
            swap32(aA, cA);
            swap32(bA, dA);
            uint4 awA = {aA, bA, cA, dA};
            bf16x8 paA = __builtin_bit_cast(bf16x8, awA);
            u32 aB  = pk2(pB[8 * k2 + 0], pB[8 * k2 + 1]);
            u32 bB  = pk2(pB[8 * k2 + 2], pB[8 * k2 + 3]);
            u32 cB2 = pk2(pB[8 * k2 + 4], pB[8 * k2 + 5]);
            u32 dB  = pk2(pB[8 * k2 + 6], pB[8 * k2 + 7]);
            swap32(aB, cB2);
            swap32(bB, dB);
            uint4 awB = {aB, bB, cB2, dB};
            bf16x8 paB = __builtin_bit_cast(bf16x8, awB);
            bf16x8 v0 = (k2 == 0) ? v00 : v01;
            bf16x8 v1 = (k2 == 0) ? v10 : v11;
            __builtin_amdgcn_s_setprio(1);
            accA0 = __builtin_amdgcn_mfma_f32_32x32x16_bf16(paA, v0, accA0, 0, 0, 0);
            accB0 = __builtin_amdgcn_mfma_f32_32x32x16_bf16(paB, v0, accB0, 0, 0, 0);
            accA1 = __builtin_amdgcn_mfma_f32_32x32x16_bf16(paA, v1, accA1, 0, 0, 0);
            accB1 = __builtin_amdgcn_mfma_f32_32x32x16_bf16(paB, v1, accB1, 0, 0, 0);
            __builtin_amdgcn_s_setprio(0);
        }
    }

    // staged reduction per j-tile: 8 waves -> 4 -> final sum by all threads
    if (w >= 4) {
#pragma unroll
        for (int r = 0; r < 16; ++r) {
            int jl = (r & 3) + 8 * (r >> 2) + 4 * hf;
            red[0][w - 4][jl * 64 + l31] = accA0[r];
            red[0][w - 4][jl * 64 + 32 + l31] = accA1[r];
            red[1][w - 4][jl * 64 + l31] = accB0[r];
            red[1][w - 4][jl * 64 + 32 + l31] = accB1[r];
        }
    }
    __syncthreads();
    if (w < 4) {
#pragma unroll
        for (int r = 0; r < 16; ++r) {
            int jl = (r & 3) + 8 * (r >> 2) + 4 * hf;
            red[0][w][jl * 64 + l31] += accA0[r];
            red[0][w][jl * 64 + 32 + l31] += accA1[r];
            red[1][w][jl * 64 + l31] += accB0[r];
            red[1][w][jl * 64 + 32 + l31] += accB1[r];
        }
    }
    __syncthreads();
    {
        const int idx = threadIdx.x * 8;          // [0, 4096)
        const int g3 = idx >> 11, e = idx & 2047;
        float vv[8];
#pragma unroll
        for (int q = 0; q < 8; ++q) {
            int ee = e + q;
            float v = red[g3][0][ee] + red[g3][1][ee] + red[g3][2][ee] + red[g3][3][ee];
            vv[q] = v / (1.f + __expf(-v));
        }
        const int jl = e >> 6, hc = e & 63;
        float* dst = out + ((size_t)b * TT + (jt0 + g3) * 32 + jl) * HH + hc;
        *(float4*)dst = make_float4(vv[0], vv[1], vv[2], vv[3]);
        *(float4*)(dst + 4) = make_float4(vv[4], vv[5], vv[6], vv[7]);
    }
}

// ---------------------------------------------------------------------------
extern "C" void kernel_launch(void* const* d_in, const int* in_sizes, int n_in,
                              void* d_out, int out_size, void* d_ws, size_t ws_size,
                              hipStream_t stream) {
    const float* X  = (const float*)d_in[0];
    const int*  dag = (const int*)d_in[1];
    const float* Wk = (const float*)d_in[2];
    const float* Wq = (const float*)d_in[3];
    const float* Wv = (const float*)d_in[4];
    float* out = (float*)d_out;

    char* ws = (char*)d_ws;
    u16*   QF    = (u16*)ws;                                // 0..2 MB (A-frag, pre-scaled)
    u16*   KF    = (u16*)(ws + (2u << 20));                 // 2..4 MB (A-frag)
    u16*   VF    = (u16*)(ws + (4u << 20));                 // 4..6 MB (B-frag, unscaled)
    u16*   VF2   = (u16*)(ws + (6u << 20));                 // 6..8 MB (B-frag, scaled)
    u32*   bits2 = (u32*)(ws + (8u << 20));                 // 8..10 MB  [jt][i]
    u32*   bitsTT= (u32*)(ws + (10u << 20));                // 10..12 MB [it][j]
    u16*   WF    = (u16*)(ws + (12u << 20));                // 192 KB (B-frag W)

    wtr_kernel<<<24, 256, 0, stream>>>(Wq, Wk, Wv, WF);
    ppF_kernel<<<512 + 342, 384, 0, stream>>>(X, WF, QF, KF, VF, dag, bits2);
    transtats_kernel<<<1280, 512, 0, stream>>>(QF, KF, bits2, VF, VF2, bitsTT);
    out_kernel<<<256, 512, 0, stream>>>(QF, KF, VF2, bitsTT, out);
}

// Round 26
// 78.156 us; speedup vs baseline: 1.1036x; 1.1036x over previous
//
#include <hip/hip_runtime.h>
#include <hip/hip_bf16.h>
#include <math.h>

#define BB 4
#define TT 4096
#define DD 512
#define HH 64
#define TW 128   // TT/32 words

typedef unsigned int u32;
typedef unsigned short u16;
typedef float f32x16 __attribute__((ext_vector_type(16)));
typedef __bf16 bf16x8 __attribute__((ext_vector_type(8)));

#define SC 0.18033688011112042f  /* 0.125 * log2(e), folded into Q at proj */

static __device__ __forceinline__ u16 f2b(float f) {
    __hip_bfloat16 h = __float2bfloat16(f);
    return __builtin_bit_cast(u16, h);
}
static __device__ __forceinline__ float b2f(u16 x) {
    return __builtin_bit_cast(float, (u32)x << 16);
}
static __device__ __forceinline__ u32 pk2(float a, float b) {
    return (u32)f2b(a) | ((u32)f2b(b) << 16);
}
static __device__ __forceinline__ bf16x8 ldf(const u16* p) {
    uint4 u = *(const uint4*)p;
    return __builtin_bit_cast(bf16x8, u);
}
static __device__ __forceinline__ bf16x8 ldsf(const u16* p) {
    uint4 u = *(const uint4*)p;
    return __builtin_bit_cast(bf16x8, u);
}
// swap high 32 lanes of a with low 32 lanes of b (both results used)
static __device__ __forceinline__ void swap32(u32& a, u32& b) {
    asm("v_permlane32_swap_b32 %0, %1" : "+v"(a), "+v"(b));
}

// Fragment-order layouts (MFMA 32x32x16 fragment: lane&31 = row/col-of-32,
// lane>>5 = k-half, 8 consecutive k per lane):
//   QF/KF: [b*128 + tile][kt=0..3][lane][8 u16]  (row = t, k = d); QF pre-scaled
//   VF:    [b*128 + tile][hg*2+k2][lane][8 u16]  (col = h, k = i-local); VF2 = scaled
//   WF:    [m][kt=0..31][nt][lane][8 u16]        (col = n, k = d)  B-frag
//   bitsR:  [row][jt]  ROW-major mask words (pack writes coalesced 256 B)
//   bitsTT: [it][j]    word = 32 i-bits for col j
//
// r26: r24 pipeline (best, 80.5us) with ONE change: pack writes bitsR
// row-major -> one coalesced 256 B full-line store per wave instead of 64
// partial-line 4 B scatters (partial-line HBM writes force RMW line fills;
// pack was transaction-bound at ~1.5 TB/s in every variant). trans/stats
// read bitsR via small L2-hot gathers (values identical).
// XCD pinning (stats/out): b = (bid&7)>>1 -> batch b owns XCD pair {2b,2b+1}.

// ---------------------------------------------------------------------------
// wtr: fp32 W[512][64] x3 -> bf16 WF B-fragment order. 24 blocks.
// ---------------------------------------------------------------------------
__global__ __launch_bounds__(256) void wtr_kernel(const float* __restrict__ Wq,
                                                  const float* __restrict__ Wk,
                                                  const float* __restrict__ Wv,
                                                  u16* __restrict__ WF) {
    const int wb = blockIdx.x;            // 0..23
    const int m = wb >> 3, sub = wb & 7;
    const float* W = (m == 0) ? Wq : (m == 1) ? Wk : Wv;
    const int t = threadIdx.x;
    const int n = sub * 8 + (t >> 5);     // 0..63
    const int kt = t & 31;
    const int l31 = n & 31, nt = n >> 5;
#pragma unroll
    for (int kk = 0; kk < 16; ++kk) {
        const int hf = kk >> 3, e = kk & 7;
        WF[(size_t)m * 32768 + kt * 1024 + nt * 512 + (hf * 32 + l31) * 8 + e]
            = f2b(W[(size_t)(kt * 16 + kk) * HH + n]);
    }
}

// ---------------------------------------------------------------------------
// ppF: heterogeneous launch. Blocks 0..511 = projF (LDS-fused X-convert +
// QKV MFMA, 384 thr); blocks 512..1877 = row-linear dag pack (3 rows/block),
// coalesced row-major bitsR store.
// ---------------------------------------------------------------------------
__global__ __launch_bounds__(384) void ppF_kernel(const float* __restrict__ X,
                                                  const u16* __restrict__ WF,
                                                  u16* __restrict__ QF,
                                                  u16* __restrict__ KF,
                                                  u16* __restrict__ VF,
                                                  const int* __restrict__ dag,
                                                  u32* __restrict__ bitsR) {
    __shared__ u16 XS[16384];          // 32 KB, A-frag order [kt][lane][8]
    if (blockIdx.x >= 512) {
        // ---- pack path (row-linear streaming, coalesced store) ----
        const int w = threadIdx.x >> 6, lane = threadIdx.x & 63;
        const int row = (blockIdx.x - 512) * 3 + (w >> 1);
        if (row >= TT) return;
        const int h = w & 1;                          // row half (2048 cols)
        const int c0 = h * 2048 + lane * 32;          // 32 consecutive cols
        const int* p = dag + (size_t)row * TT + c0;
        u32 mk = 0;
#pragma unroll
        for (int q = 0; q < 8; ++q) {
            int4 v = *(const int4*)(p + q * 4);
            mk |= (v.x != 0 ? 1u : 0u) << (q * 4);
            mk |= (v.y != 0 ? 1u : 0u) << (q * 4 + 1);
            mk |= (v.z != 0 ? 1u : 0u) << (q * 4 + 2);
            mk |= (v.w != 0 ? 1u : 0u) << (q * 4 + 3);
        }
        // row-major: one coalesced 256 B full-line store per wave
        bitsR[(size_t)row * 128 + h * 64 + lane] = mk;
        return;
    }
    // ---- projF path ----
    const int tile = blockIdx.x;
    const int t = threadIdx.x;
    // phase 1: stage X tile (32 rows x 512 cols fp32) -> bf16 A-frag LDS
    for (int g = t; g < 4096; g += 384) {
        const int rl = g >> 7, c4 = g & 127;
        const int d0 = c4 * 4;
        const int kt = d0 >> 4, hf = (d0 >> 3) & 1, e0 = d0 & 7;
        float4 v = *(const float4*)(X + ((size_t)tile * 32 + rl) * DD + d0);
        u32* dst = (u32*)&XS[kt * 512 + (hf * 32 + rl) * 8 + e0];
        dst[0] = pk2(v.x, v.y);
        dst[1] = pk2(v.z, v.w);
    }
    __syncthreads();
    // phase 2: MFMA
    const int w = t >> 6, lane = t & 63;
    const int m = w >> 1, nt = w & 1;
    const int l31 = lane & 31, hf = lane >> 5;
    const u16* xs = XS + lane * 8;
    const u16* wf = WF + (size_t)m * 32768 + nt * 512 + lane * 8;

    f32x16 acc = {};
#pragma unroll 8
    for (int kt = 0; kt < 32; ++kt) {
        bf16x8 xa = ldsf(xs + kt * 512);
        acc = __builtin_amdgcn_mfma_f32_32x32x16_bf16(xa, ldf(wf + kt * 1024), acc, 0, 0, 0);
    }
    const float sc = (m == 0) ? SC : 1.0f;
    if (m < 2) {
        // A-fragment order: row = tile*32+rl, n = nt*32+l31
        u16* dst = (m == 0) ? QF : KF;
        const int kth = l31 >> 4, hfp = (l31 >> 3) & 1, e = l31 & 7;
#pragma unroll
        for (int r = 0; r < 16; ++r) {
            int rl = (r & 3) + 8 * (r >> 2) + 4 * hf;
            dst[(size_t)tile * 2048 + (nt * 2 + kth) * 512 + (rl + hfp * 32) * 8 + e]
                = f2b(acc[r] * sc);
        }
    } else {
        // B-fragment order: col = h = nt*32+l31, k = i-local = rl
#pragma unroll
        for (int r = 0; r < 16; ++r) {
            int rl = (r & 3) + 8 * (r >> 2) + 4 * hf;
            VF[(size_t)tile * 2048 + (nt * 2 + (rl >> 4)) * 512
               + (l31 + ((rl >> 3) & 1) * 32) * 8 + (rl & 7)] = f2b(acc[r]);
        }
    }
}

// ---------------------------------------------------------------------------
// transtats: heterogeneous launch of two INDEPENDENT jobs.
// Blocks 0..255   = stats (+V-scale) path, 512 thr, XCD-pinned.
// Blocks 256..1279 = bit-transpose path (reads bitsR, writes bitsTT).
// ---------------------------------------------------------------------------
__global__ __launch_bounds__(512, 2) void transtats_kernel(const u16* __restrict__ QF,
                                                           const u16* __restrict__ KF,
                                                           const u32* __restrict__ bitsR,
                                                           const u16* __restrict__ VF,
                                                           u16* __restrict__ VF2,
                                                           u32* __restrict__ bitsTT) {
    __shared__ float Lsh[8][128];
    __shared__ float cSh[64];
    if (blockIdx.x >= 256) {
        // ---------------- trans path ----------------
        const int w = threadIdx.x >> 6, lane = threadIdx.x & 63;
        const int l31 = lane & 31, grp = lane >> 5;
        const int g = (blockIdx.x - 256) * 16 + w * 2 + grp;   // 0..16383
        const int it = g >> 7, jt = g & 127;
        u32 S = bitsR[(size_t)(it * 32 + l31) * 128 + jt];    // word (jt, row)
        u32 sel = 0;
        const bool low = (lane < 32);
#pragma unroll
        for (int jb = 0; jb < 32; ++jb) {
            unsigned long long m = __ballot((S >> jb) & 1);
            u32 pick = low ? (u32)m : (u32)(m >> 32);
            sel = (l31 == jb) ? pick : sel;
        }
        bitsTT[(size_t)it * TT + jt * 32 + l31] = sel;
        return;
    }
    // ---------------- stats path ----------------
    const int bid = blockIdx.x;
    const int b = (bid & 7) >> 1;
    const int u = (bid & 1) * 32 + (bid >> 3);
    const int itg0 = u * 2;
    const int i0 = itg0 * 32;
    const int w = threadIdx.x >> 6, lane = threadIdx.x & 63;
    const int l31 = lane & 31, hf = lane >> 5;

    bf16x8 qfA[4], qfB[4];
    const u16* qbase = QF + (size_t)(b * 128 + itg0) * 2048 + lane * 8;
#pragma unroll
    for (int kt = 0; kt < 4; ++kt) {
        qfA[kt] = ldf(qbase + kt * 512);
        qfB[kt] = ldf(qbase + 2048 + kt * 512);
    }

    const u16* kf0 = KF + (size_t)b * 128 * 2048 + lane * 8;

    float LpA = 0.f, LpB = 0.f;
    for (int t = 0; t < 16; ++t) {
        const int jt = w + t * 8;
        const u16* kb = kf0 + (size_t)jt * 2048;
        u32 mwA = bitsR[(size_t)(i0 + l31) * 128 + jt];
        u32 mwB = bitsR[(size_t)(i0 + 32 + l31) * 128 + jt];

        bf16x8 k0 = ldf(kb), k1 = ldf(kb + 512), k2 = ldf(kb + 1024), k3 = ldf(kb + 1536);
        __builtin_amdgcn_s_setprio(1);
        f32x16 sA = {}, sB = {};
        sA = __builtin_amdgcn_mfma_f32_32x32x16_bf16(k0, qfA[0], sA, 0, 0, 0);
        sB = __builtin_amdgcn_mfma_f32_32x32x16_bf16(k0, qfB[0], sB, 0, 0, 0);
        sA = __builtin_amdgcn_mfma_f32_32x32x16_bf16(k1, qfA[1], sA, 0, 0, 0);
        sB = __builtin_amdgcn_mfma_f32_32x32x16_bf16(k1, qfB[1], sB, 0, 0, 0);
        sA = __builtin_amdgcn_mfma_f32_32x32x16_bf16(k2, qfA[2], sA, 0, 0, 0);
        sB = __builtin_amdgcn_mfma_f32_32x32x16_bf16(k2, qfB[2], sB, 0, 0, 0);
        sA = __builtin_amdgcn_mfma_f32_32x32x16_bf16(k3, qfA[3], sA, 0, 0, 0);
        sB = __builtin_amdgcn_mfma_f32_32x32x16_bf16(k3, qfB[3], sB, 0, 0, 0);
        __builtin_amdgcn_s_setprio(0);
        u32 mrA = __builtin_amdgcn_alignbit(mwA, mwA, hf * 4);  // rotr by 4*hf
        u32 mrB = __builtin_amdgcn_alignbit(mwB, mwB, hf * 4);
#pragma unroll
        for (int r = 0; r < 16; ++r) {
            const int pos = (r & 3) + 8 * (r >> 2);
            float eA = __builtin_amdgcn_exp2f(sA[r]);
            float eB = __builtin_amdgcn_exp2f(sB[r]);
            LpA += ((mrA >> pos) & 1) ? eA : 0.f;
            LpB += ((mrB >> pos) & 1) ? eB : 0.f;
        }
    }
    Lsh[w][lane] = LpA;
    Lsh[w][64 + lane] = LpB;
    __syncthreads();
    if (threadIdx.x < 64) {
        const int g = threadIdx.x >> 5, il = threadIdx.x & 31;
        float L = 0.f;
#pragma unroll
        for (int q = 0; q < 8; ++q) L += Lsh[q][g * 64 + il] + Lsh[q][g * 64 + il + 32];
        cSh[g * 32 + il] = (L > 0.f) ? 1.f / L : 0.f;
    }
    __syncthreads();
    // scale the block's two VF tiles (512 uint4) into VF2; 1 uint4/thread
    {
        const int tl = threadIdx.x >> 8;          // 0..1 tile-local
        const int rem = threadIdx.x & 255;
        const int q = rem >> 6, ln = rem & 63;
        const int ib = tl * 32 + (q & 1) * 16 + (ln >> 5) * 8;
        float4 c0 = *(const float4*)&cSh[ib];
        float4 c1 = *(const float4*)&cSh[ib + 4];
        const size_t off = (size_t)(b * 128 + itg0 + tl) * 2048 + q * 512 + ln * 8;
        uint4 v = *(const uint4*)(VF + off);
        u16* ve = (u16*)&v;
        ve[0] = f2b(b2f(ve[0]) * c0.x);
        ve[1] = f2b(b2f(ve[1]) * c0.y);
        ve[2] = f2b(b2f(ve[2]) * c0.z);
        ve[3] = f2b(b2f(ve[3]) * c0.w);
        ve[4] = f2b(b2f(ve[4]) * c1.x);
        ve[5] = f2b(b2f(ve[5]) * c1.y);
        ve[6] = f2b(b2f(ve[6]) * c1.z);
        ve[7] = f2b(b2f(ve[7]) * c1.w);
        *(uint4*)(VF2 + off) = v;
    }
}

// ---------------------------------------------------------------------------
// Output: TWO adjacent 32-j tiles per block; each Q/V load feeds both S/PV
// chains. Block 512 thr (8 waves), 8-way i-split. Grid 256. XCD-pinned.
// ---------------------------------------------------------------------------
__global__ __launch_bounds__(512, 2) void out_kernel(const u16* __restrict__ QF,
                                                     const u16* __restrict__ KF,
                                                     const u16* __restrict__ VF2,
                                                     const u32* __restrict__ bitsTT,
                                                     float* __restrict__ out) {
    __shared__ float red[2][4][2048];
    const int bid = blockIdx.x;
    const int b = (bid & 7) >> 1;
    const int u = (bid & 1) * 32 + (bid >> 3);
    const int jt0 = u * 2;
    const int j0 = jt0 * 32;
    const int w = threadIdx.x >> 6, lane = threadIdx.x & 63;
    const int l31 = lane & 31, hf = lane >> 5;

    bf16x8 kfA[4], kfB[4];
    const u16* kbase = KF + (size_t)(b * 128 + jt0) * 2048 + lane * 8;
#pragma unroll
    for (int kt = 0; kt < 4; ++kt) {
        kfA[kt] = ldf(kbase + kt * 512);
        kfB[kt] = ldf(kbase + 2048 + kt * 512);
    }

    const u16* qf0 = QF + (size_t)b * 128 * 2048 + lane * 8;
    const u16* vf0 = VF2 + (size_t)b * 128 * 2048 + lane * 8;

    f32x16 accA0 = {}, accA1 = {}, accB0 = {}, accB1 = {};

    for (int t = 0; t < 16; ++t) {
        const int it = w + t * 8;
        const u16* qb = qf0 + (size_t)it * 2048;
        const u16* vb = vf0 + (size_t)it * 2048;
        u32 mwA = bitsTT[(size_t)it * TT + j0 + l31];
        u32 mwB = bitsTT[(size_t)it * TT + j0 + 32 + l31];

        bf16x8 q0 = ldf(qb), q1 = ldf(qb + 512), q2 = ldf(qb + 1024), q3 = ldf(qb + 1536);
        __builtin_amdgcn_s_setprio(1);
        f32x16 sA = {}, sB = {};
        sA = __builtin_amdgcn_mfma_f32_32x32x16_bf16(q0, kfA[0], sA, 0, 0, 0);
        sB = __builtin_amdgcn_mfma_f32_32x32x16_bf16(q0, kfB[0], sB, 0, 0, 0);
        sA = __builtin_amdgcn_mfma_f32_32x32x16_bf16(q1, kfA[1], sA, 0, 0, 0);
        sB = __builtin_amdgcn_mfma_f32_32x32x16_bf16(q1, kfB[1], sB, 0, 0, 0);
        sA = __builtin_amdgcn_mfma_f32_32x32x16_bf16(q2, kfA[2], sA, 0, 0, 0);
        sB = __builtin_amdgcn_mfma_f32_32x32x16_bf16(q2, kfB[2], sB, 0, 0, 0);
        sA = __builtin_amdgcn_mfma_f32_32x32x16_bf16(q3, kfA[3], sA, 0, 0, 0);
        sB = __builtin_amdgcn_mfma_f32_32x32x16_bf16(q3, kfB[3], sB, 0, 0, 0);
        __builtin_amdgcn_s_setprio(0);

        u32 mrA = __builtin_amdgcn_alignbit(mwA, mwA, hf * 4);  // rotr by 4*hf
        u32 mrB = __builtin_amdgcn_alignbit(mwB, mwB, hf * 4);

        float pA[16], pB[16];
#pragma unroll
        for (int r = 0; r < 16; ++r) {
            const int pos = (r & 3) + 8 * (r >> 2);
            float eA = __builtin_amdgcn_exp2f(sA[r]);
            float eB = __builtin_amdgcn_exp2f(sB[r]);
            pA[r] = ((mrA >> pos) & 1) ? eA : 0.f;
            pB[r] = ((mrB >> pos) & 1) ? eB : 0.f;
        }

        bf16x8 v00 = ldf(vb), v01 = ldf(vb + 512), v10 = ldf(vb + 1024), v11 = ldf(vb + 1536);

#pragma unroll
        for (int k2 = 0; k2 < 2; ++k2) {
            u32 aA  = pk2(pA[8 * k2 + 0], pA[8 * k2 + 1]);
            u32 bA  = pk2(pA[8 * k2 + 2], pA[8 * k2 + 3]);
            u32 cA  = pk2(pA[8 * k2 + 4], pA[8 * k2 + 5]);
            u32 dA  = pk2(pA[8 * k2 + 6], pA[8 * k2 + 7]);
            swap32(aA, cA);
            swap32(bA, dA);
            uint4 awA = {aA, bA, cA, dA};
            bf16x8 paA = __builtin_bit_cast(bf16x8, awA);
            u32 aB  = pk2(pB[8 * k2 + 0], pB[8 * k2 + 1]);
            u32 bB  = pk2(pB[8 * k2 + 2], pB[8 * k2 + 3]);
            u32 cB2 = pk2(pB[8 * k2 + 4], pB[8 * k2 + 5]);
            u32 dB  = pk2(pB[8 * k2 + 6], pB[8 * k2 + 7]);
            swap32(aB, cB2);
            swap32(bB, dB);
            uint4 awB = {aB, bB, cB2, dB};
            bf16x8 paB = __builtin_bit_cast(bf16x8, awB);
            bf16x8 v0 = (k2 == 0) ? v00 : v01;
            bf16x8 v1 = (k2 == 0) ? v10 : v11;
            __builtin_amdgcn_s_setprio(1);
            accA0 = __builtin_amdgcn_mfma_f32_32x32x16_bf16(paA, v0, accA0, 0, 0, 0);
            accB0 = __builtin_amdgcn_mfma_f32_32x32x16_bf16(paB, v0, accB0, 0, 0, 0);
            accA1 = __builtin_amdgcn_mfma_f32_32x32x16_bf16(paA, v1, accA1, 0, 0, 0);
            accB1 = __builtin_amdgcn_mfma_f32_32x32x16_bf16(paB, v1, accB1, 0, 0, 0);
            __builtin_amdgcn_s_setprio(0);
        }
    }

    // staged reduction per j-tile: 8 waves -> 4 -> final sum by all threads
    if (w >= 4) {
#pragma unroll
        for (int r = 0; r < 16; ++r) {
            int jl = (r & 3) + 8 * (r >> 2) + 4 * hf;
            red[0][w - 4][jl * 64 + l31] = accA0[r];
            red[0][w - 4][jl * 64 + 32 + l31] = accA1[r];
            red[1][w - 4][jl * 64 + l31] = accB0[r];
            red[1][w - 4][jl * 64 + 32 + l31] = accB1[r];
        }
    }
    __syncthreads();
    if (w < 4) {
#pragma unroll
        for (int r = 0; r < 16; ++r) {
            int jl = (r & 3) + 8 * (r >> 2) + 4 * hf;
            red[0][w][jl * 64 + l31] += accA0[r];
            red[0][w][jl * 64 + 32 + l31] += accA1[r];
            red[1][w][jl * 64 + l31] += accB0[r];
            red[1][w][jl * 64 + 32 + l31] += accB1[r];
        }
    }
    __syncthreads();
    {
        const int idx = threadIdx.x * 8;          // [0, 4096)
        const int g3 = idx >> 11, e = idx & 2047;
        float vv[8];
#pragma unroll
        for (int q = 0; q < 8; ++q) {
            int ee = e + q;
            float v = red[g3][0][ee] + red[g3][1][ee] + red[g3][2][ee] + red[g3][3][ee];
            vv[q] = v / (1.f + __expf(-v));
        }
        const int jl = e >> 6, hc = e & 63;
        float* dst = out + ((size_t)b * TT + (jt0 + g3) * 32 + jl) * HH + hc;
        *(float4*)dst = make_float4(vv[0], vv[1], vv[2], vv[3]);
        *(float4*)(dst + 4) = make_float4(vv[4], vv[5], vv[6], vv[7]);
    }
}

// ---------------------------------------------------------------------------
extern "C" void kernel_launch(void* const* d_in, const int* in_sizes, int n_in,
                              void* d_out, int out_size, void* d_ws, size_t ws_size,
                              hipStream_t stream) {
    const float* X  = (const float*)d_in[0];
    const int*  dag = (const int*)d_in[1];
    const float* Wk = (const float*)d_in[2];
    const float* Wq = (const float*)d_in[3];
    const float* Wv = (const float*)d_in[4];
    float* out = (float*)d_out;

    char* ws = (char*)d_ws;
    u16*   QF    = (u16*)ws;                                // 0..2 MB (A-frag, pre-scaled)
    u16*   KF    = (u16*)(ws + (2u << 20));                 // 2..4 MB (A-frag)
    u16*   VF    = (u16*)(ws + (4u << 20));                 // 4..6 MB (B-frag, unscaled)
    u16*   VF2   = (u16*)(ws + (6u << 20));                 // 6..8 MB (B-frag, scaled)
    u32*   bitsR = (u32*)(ws + (8u << 20));                 // 8..10 MB  [row][jt]
    u32*   bitsTT= (u32*)(ws + (10u << 20));                // 10..12 MB [it][j]
    u16*   WF    = (u16*)(ws + (12u << 20));                // 192 KB (B-frag W)

    wtr_kernel<<<24, 256, 0, stream>>>(Wq, Wk, Wv, WF);
    ppF_kernel<<<512 + 1366, 384, 0, stream>>>(X, WF, QF, KF, VF, dag, bitsR);
    transtats_kernel<<<1280, 512, 0, stream>>>(QF, KF, bitsR, VF, VF2, bitsTT);
    out_kernel<<<256, 512, 0, stream>>>(QF, KF, VF2, bitsTT, out);
}

// Round 27
// 77.413 us; speedup vs baseline: 1.1141x; 1.0096x over previous
//
#include <hip/hip_runtime.h>
#include <hip/hip_bf16.h>
#include <math.h>

#define BB 4
#define TT 4096
#define DD 512
#define HH 64
#define TW 128   // TT/32 words

typedef unsigned int u32;
typedef unsigned short u16;
typedef float f32x16 __attribute__((ext_vector_type(16)));
typedef __bf16 bf16x8 __attribute__((ext_vector_type(8)));

#define SC 0.18033688011112042f  /* 0.125 * log2(e), folded into Q at proj */

static __device__ __forceinline__ u16 f2b(float f) {
    __hip_bfloat16 h = __float2bfloat16(f);
    return __builtin_bit_cast(u16, h);
}
static __device__ __forceinline__ float b2f(u16 x) {
    return __builtin_bit_cast(float, (u32)x << 16);
}
static __device__ __forceinline__ u32 pk2(float a, float b) {
    return (u32)f2b(a) | ((u32)f2b(b) << 16);
}
static __device__ __forceinline__ bf16x8 ldf(const u16* p) {
    uint4 u = *(const uint4*)p;
    return __builtin_bit_cast(bf16x8, u);
}
static __device__ __forceinline__ bf16x8 ldsf(const u16* p) {
    uint4 u = *(const uint4*)p;
    return __builtin_bit_cast(bf16x8, u);
}
// swap high 32 lanes of a with low 32 lanes of b (both results used)
static __device__ __forceinline__ void swap32(u32& a, u32& b) {
    asm("v_permlane32_swap_b32 %0, %1" : "+v"(a), "+v"(b));
}

// Fragment-order layouts (MFMA 32x32x16 fragment: lane&31 = row/col-of-32,
// lane>>5 = k-half, 8 consecutive k per lane):
//   QF/KF: [b*128 + tile][kt=0..3][lane][8 u16]  (row = t, k = d); QF pre-scaled
//   VF:    [b*128 + tile][hg*2+k2][lane][8 u16]  (col = h, k = i-local); VF2 = scaled
//   WF:    [m][kt=0..31][nt][lane][8 u16]        (col = n, k = d)  B-frag
//   bitsR:  [row][jt]  ROW-major mask words (pack writes coalesced 256 B)
//   bitsTT: [it][j]    word = 32 i-bits for col j
//
// r27: r26 pipeline with pack's READ side fixed. Old pack: lane reads 32
// consecutive ints (128 B/lane) -> within each int4 load the lane stride is
// a full cache line -> 64 partial-line transactions per load (4-8x
// amplification; every pack variant pinned at ~1.5 TB/s). New pack: per 8 KB
// unit, 8 truly coalesced int4 loads -> same-wave LDS bounce with XOR
// swizzle addr^(((addr>>7)&7)<<4) (bijective, conflict-free both sides,
// rule #21) -> lane reads back its 128 B -> word -> coalesced store.
// XCD pinning (stats/out): b = (bid&7)>>1 -> batch b owns XCD pair {2b,2b+1}.

// ---------------------------------------------------------------------------
// wtr: fp32 W[512][64] x3 -> bf16 WF B-fragment order. 24 blocks.
// ---------------------------------------------------------------------------
__global__ __launch_bounds__(256) void wtr_kernel(const float* __restrict__ Wq,
                                                  const float* __restrict__ Wk,
                                                  const float* __restrict__ Wv,
                                                  u16* __restrict__ WF) {
    const int wb = blockIdx.x;            // 0..23
    const int m = wb >> 3, sub = wb & 7;
    const float* W = (m == 0) ? Wq : (m == 1) ? Wk : Wv;
    const int t = threadIdx.x;
    const int n = sub * 8 + (t >> 5);     // 0..63
    const int kt = t & 31;
    const int l31 = n & 31, nt = n >> 5;
#pragma unroll
    for (int kk = 0; kk < 16; ++kk) {
        const int hf = kk >> 3, e = kk & 7;
        WF[(size_t)m * 32768 + kt * 1024 + nt * 512 + (hf * 32 + l31) * 8 + e]
            = f2b(W[(size_t)(kt * 16 + kk) * HH + n]);
    }
}

// ---------------------------------------------------------------------------
// ppF: heterogeneous launch. Blocks 0..511 = projF (LDS-fused X-convert +
// QKV MFMA, 384 thr); blocks 512..1535 = pack (4 waves x 2 units, LDS-bounce).
// ---------------------------------------------------------------------------
__global__ __launch_bounds__(384) void ppF_kernel(const float* __restrict__ X,
                                                  const u16* __restrict__ WF,
                                                  u16* __restrict__ QF,
                                                  u16* __restrict__ KF,
                                                  u16* __restrict__ VF,
                                                  const int* __restrict__ dag,
                                                  u32* __restrict__ bitsR) {
    __shared__ u16 XS[16384];          // 32 KB; pack: 4 waves x 8 KB slices
    if (blockIdx.x >= 512) {
        // ---- pack path: coalesced reads + same-wave swizzled LDS bounce ----
        const int w = threadIdx.x >> 6, lane = threadIdx.x & 63;
        if (w >= 4) return;
        char* wbuf = (char*)XS + w * 8192;           // this wave's 8 KB
        const int base = (blockIdx.x - 512) * 8;     // 8 units per block
#pragma unroll
        for (int uu = 0; uu < 2; ++uu) {
            const int u = base + uu * 4 + w;         // 0..8191
            const int row = u >> 1, h = u & 1;
            const int* src = dag + (size_t)row * TT + h * 2048;
            // phase A: 8 coalesced int4 loads (lane stride 16 B -> full lines),
            // swizzled LDS writes (8-lane groups stay 128 B-contiguous).
#pragma unroll
            for (int q = 0; q < 8; ++q) {
                int4 v = *(const int4*)(src + q * 256 + lane * 4);
                const int boff = q * 1024 + lane * 16;
                const int swz = boff ^ (((lane >> 3) & 7) << 4);
                *(int4*)(wbuf + swz) = v;
            }
            // phase B: lane reads back ITS 128 B (cols lane*32..+31) via
            // swizzled ds_read_b128 (offsets (q^lane)&7 -> conflict-free).
            u32 mk = 0;
#pragma unroll
            for (int q = 0; q < 8; ++q) {
                const int boff = lane * 128 + q * 16;
                const int swz = boff ^ ((lane & 7) << 4);
                int4 v = *(const int4*)(wbuf + swz);
                mk |= (v.x != 0 ? 1u : 0u) << (q * 4);
                mk |= (v.y != 0 ? 1u : 0u) << (q * 4 + 1);
                mk |= (v.z != 0 ? 1u : 0u) << (q * 4 + 2);
                mk |= (v.w != 0 ? 1u : 0u) << (q * 4 + 3);
            }
            bitsR[(size_t)row * 128 + h * 64 + lane] = mk;   // coalesced
        }
        return;
    }
    // ---- projF path ----
    const int tile = blockIdx.x;
    const int t = threadIdx.x;
    // phase 1: stage X tile (32 rows x 512 cols fp32) -> bf16 A-frag LDS
    for (int g = t; g < 4096; g += 384) {
        const int rl = g >> 7, c4 = g & 127;
        const int d0 = c4 * 4;
        const int kt = d0 >> 4, hf = (d0 >> 3) & 1, e0 = d0 & 7;
        float4 v = *(const float4*)(X + ((size_t)tile * 32 + rl) * DD + d0);
        u32* dst = (u32*)&XS[kt * 512 + (hf * 32 + rl) * 8 + e0];
        dst[0] = pk2(v.x, v.y);
        dst[1] = pk2(v.z, v.w);
    }
    __syncthreads();
    // phase 2: MFMA
    const int w = t >> 6, lane = t & 63;
    const int m = w >> 1, nt = w & 1;
    const int l31 = lane & 31, hf = lane >> 5;
    const u16* xs = XS + lane * 8;
    const u16* wf = WF + (size_t)m * 32768 + nt * 512 + lane * 8;

    f32x16 acc = {};
#pragma unroll 8
    for (int kt = 0; kt < 32; ++kt) {
        bf16x8 xa = ldsf(xs + kt * 512);
        acc = __builtin_amdgcn_mfma_f32_32x32x16_bf16(xa, ldf(wf + kt * 1024), acc, 0, 0, 0);
    }
    const float sc = (m == 0) ? SC : 1.0f;
    if (m < 2) {
        // A-fragment order: row = tile*32+rl, n = nt*32+l31
        u16* dst = (m == 0) ? QF : KF;
        const int kth = l31 >> 4, hfp = (l31 >> 3) & 1, e = l31 & 7;
#pragma unroll
        for (int r = 0; r < 16; ++r) {
            int rl = (r & 3) + 8 * (r >> 2) + 4 * hf;
            dst[(size_t)tile * 2048 + (nt * 2 + kth) * 512 + (rl + hfp * 32) * 8 + e]
                = f2b(acc[r] * sc);
        }
    } else {
        // B-fragment order: col = h = nt*32+l31, k = i-local = rl
#pragma unroll
        for (int r = 0; r < 16; ++r) {
            int rl = (r & 3) + 8 * (r >> 2) + 4 * hf;
            VF[(size_t)tile * 2048 + (nt * 2 + (rl >> 4)) * 512
               + (l31 + ((rl >> 3) & 1) * 32) * 8 + (rl & 7)] = f2b(acc[r]);
        }
    }
}

// ---------------------------------------------------------------------------
// transtats: heterogeneous launch of two INDEPENDENT jobs.
// Blocks 0..255   = stats (+V-scale) path, 512 thr, XCD-pinned.
// Blocks 256..1279 = bit-transpose path (reads bitsR, writes bitsTT).
// ---------------------------------------------------------------------------
__global__ __launch_bounds__(512, 2) void transtats_kernel(const u16* __restrict__ QF,
                                                           const u16* __restrict__ KF,
                                                           const u32* __restrict__ bitsR,
                                                           const u16* __restrict__ VF,
                                                           u16* __restrict__ VF2,
                                                           u32* __restrict__ bitsTT) {
    __shared__ float Lsh[8][128];
    __shared__ float cSh[64];
    if (blockIdx.x >= 256) {
        // ---------------- trans path ----------------
        const int w = threadIdx.x >> 6, lane = threadIdx.x & 63;
        const int l31 = lane & 31, grp = lane >> 5;
        const int g = (blockIdx.x - 256) * 16 + w * 2 + grp;   // 0..16383
        const int it = g >> 7, jt = g & 127;
        u32 S = bitsR[(size_t)(it * 32 + l31) * 128 + jt];    // word (jt, row)
        u32 sel = 0;
        const bool low = (lane < 32);
#pragma unroll
        for (int jb = 0; jb < 32; ++jb) {
            unsigned long long m = __ballot((S >> jb) & 1);
            u32 pick = low ? (u32)m : (u32)(m >> 32);
            sel = (l31 == jb) ? pick : sel;
        }
        bitsTT[(size_t)it * TT + jt * 32 + l31] = sel;
        return;
    }
    // ---------------- stats path ----------------
    const int bid = blockIdx.x;
    const int b = (bid & 7) >> 1;
    const int u = (bid & 1) * 32 + (bid >> 3);
    const int itg0 = u * 2;
    const int i0 = itg0 * 32;
    const int w = threadIdx.x >> 6, lane = threadIdx.x & 63;
    const int l31 = lane & 31, hf = lane >> 5;

    bf16x8 qfA[4], qfB[4];
    const u16* qbase = QF + (size_t)(b * 128 + itg0) * 2048 + lane * 8;
#pragma unroll
    for (int kt = 0; kt < 4; ++kt) {
        qfA[kt] = ldf(qbase + kt * 512);
        qfB[kt] = ldf(qbase + 2048 + kt * 512);
    }

    const u16* kf0 = KF + (size_t)b * 128 * 2048 + lane * 8;

    float LpA = 0.f, LpB = 0.f;
    for (int t = 0; t < 16; ++t) {
        const int jt = w + t * 8;
        const u16* kb = kf0 + (size_t)jt * 2048;
        u32 mwA = bitsR[(size_t)(i0 + l31) * 128 + jt];
        u32 mwB = bitsR[(size_t)(i0 + 32 + l31) * 128 + jt];

        bf16x8 k0 = ldf(kb), k1 = ldf(kb + 512), k2 = ldf(kb + 1024), k3 = ldf(kb + 1536);
        __builtin_amdgcn_s_setprio(1);
        f32x16 sA = {}, sB = {};
        sA = __builtin_amdgcn_mfma_f32_32x32x16_bf16(k0, qfA[0], sA, 0, 0, 0);
        sB = __builtin_amdgcn_mfma_f32_32x32x16_bf16(k0, qfB[0], sB, 0, 0, 0);
        sA = __builtin_amdgcn_mfma_f32_32x32x16_bf16(k1, qfA[1], sA, 0, 0, 0);
        sB = __builtin_amdgcn_mfma_f32_32x32x16_bf16(k1, qfB[1], sB, 0, 0, 0);
        sA = __builtin_amdgcn_mfma_f32_32x32x16_bf16(k2, qfA[2], sA, 0, 0, 0);
        sB = __builtin_amdgcn_mfma_f32_32x32x16_bf16(k2, qfB[2], sB, 0, 0, 0);
        sA = __builtin_amdgcn_mfma_f32_32x32x16_bf16(k3, qfA[3], sA, 0, 0, 0);
        sB = __builtin_amdgcn_mfma_f32_32x32x16_bf16(k3, qfB[3], sB, 0, 0, 0);
        __builtin_amdgcn_s_setprio(0);
        u32 mrA = __builtin_amdgcn_alignbit(mwA, mwA, hf * 4);  // rotr by 4*hf
        u32 mrB = __builtin_amdgcn_alignbit(mwB, mwB, hf * 4);
#pragma unroll
        for (int r = 0; r < 16; ++r) {
            const int pos = (r & 3) + 8 * (r >> 2);
            float eA = __builtin_amdgcn_exp2f(sA[r]);
            float eB = __builtin_amdgcn_exp2f(sB[r]);
            LpA += ((mrA >> pos) & 1) ? eA : 0.f;
            LpB += ((mrB >> pos) & 1) ? eB : 0.f;
        }
    }
    Lsh[w][lane] = LpA;
    Lsh[w][64 + lane] = LpB;
    __syncthreads();
    if (threadIdx.x < 64) {
        const int g = threadIdx.x >> 5, il = threadIdx.x & 31;
        float L = 0.f;
#pragma unroll
        for (int q = 0; q < 8; ++q) L += Lsh[q][g * 64 + il] + Lsh[q][g * 64 + il + 32];
        cSh[g * 32 + il] = (L > 0.f) ? 1.f / L : 0.f;
    }
    __syncthreads();
    // scale the block's two VF tiles (512 uint4) into VF2; 1 uint4/thread
    {
        const int tl = threadIdx.x >> 8;          // 0..1 tile-local
        const int rem = threadIdx.x & 255;
        const int q = rem >> 6, ln = rem & 63;
        const int ib = tl * 32 + (q & 1) * 16 + (ln >> 5) * 8;
        float4 c0 = *(const float4*)&cSh[ib];
        float4 c1 = *(const float4*)&cSh[ib + 4];
        const size_t off = (size_t)(b * 128 + itg0 + tl) * 2048 + q * 512 + ln * 8;
        uint4 v = *(const uint4*)(VF + off);
        u16* ve = (u16*)&v;
        ve[0] = f2b(b2f(ve[0]) * c0.x);
        ve[1] = f2b(b2f(ve[1]) * c0.y);
        ve[2] = f2b(b2f(ve[2]) * c0.z);
        ve[3] = f2b(b2f(ve[3]) * c0.w);
        ve[4] = f2b(b2f(ve[4]) * c1.x);
        ve[5] = f2b(b2f(ve[5]) * c1.y);
        ve[6] = f2b(b2f(ve[6]) * c1.z);
        ve[7] = f2b(b2f(ve[7]) * c1.w);
        *(uint4*)(VF2 + off) = v;
    }
}

// ---------------------------------------------------------------------------
// Output: TWO adjacent 32-j tiles per block; each Q/V load feeds both S/PV
// chains. Block 512 thr (8 waves), 8-way i-split. Grid 256. XCD-pinned.
// ---------------------------------------------------------------------------
__global__ __launch_bounds__(512, 2) void out_kernel(const u16* __restrict__ QF,
                                                     const u16* __restrict__ KF,
                                                     const u16* __restrict__ VF2,
                                                     const u32* __restrict__ bitsTT,
                                                     float* __restrict__ out) {
    __shared__ float red[2][4][2048];
    const int bid = blockIdx.x;
    const int b = (bid & 7) >> 1;
    const int u = (bid & 1) * 32 + (bid >> 3);
    const int jt0 = u * 2;
    const int j0 = jt0 * 32;
    const int w = threadIdx.x >> 6, lane = threadIdx.x & 63;
    const int l31 = lane & 31, hf = lane >> 5;

    bf16x8 kfA[4], kfB[4];
    const u16* kbase = KF + (size_t)(b * 128 + jt0) * 2048 + lane * 8;
#pragma unroll
    for (int kt = 0; kt < 4; ++kt) {
        kfA[kt] = ldf(kbase + kt * 512);
        kfB[kt] = ldf(kbase + 2048 + kt * 512);
    }

    const u16* qf0 = QF + (size_t)b * 128 * 2048 + lane * 8;
    const u16* vf0 = VF2 + (size_t)b * 128 * 2048 + lane * 8;

    f32x16 accA0 = {}, accA1 = {}, accB0 = {}, accB1 = {};

    for (int t = 0; t < 16; ++t) {
        const int it = w + t * 8;
        const u16* qb = qf0 + (size_t)it * 2048;
        const u16* vb = vf0 + (size_t)it * 2048;
        u32 mwA = bitsTT[(size_t)it * TT + j0 + l31];
        u32 mwB = bitsTT[(size_t)it * TT + j0 + 32 + l31];

        bf16x8 q0 = ldf(qb), q1 = ldf(qb + 512), q2 = ldf(qb + 1024), q3 = ldf(qb + 1536);
        __builtin_amdgcn_s_setprio(1);
        f32x16 sA = {}, sB = {};
        sA = __builtin_amdgcn_mfma_f32_32x32x16_bf16(q0, kfA[0], sA, 0, 0, 0);
        sB = __builtin_amdgcn_mfma_f32_32x32x16_bf16(q0, kfB[0], sB, 0, 0, 0);
        sA = __builtin_amdgcn_mfma_f32_32x32x16_bf16(q1, kfA[1], sA, 0, 0, 0);
        sB = __builtin_amdgcn_mfma_f32_32x32x16_bf16(q1, kfB[1], sB, 0, 0, 0);
        sA = __builtin_amdgcn_mfma_f32_32x32x16_bf16(q2, kfA[2], sA, 0, 0, 0);
        sB = __builtin_amdgcn_mfma_f32_32x32x16_bf16(q2, kfB[2], sB, 0, 0, 0);
        sA = __builtin_amdgcn_mfma_f32_32x32x16_bf16(q3, kfA[3], sA, 0, 0, 0);
        sB = __builtin_amdgcn_mfma_f32_32x32x16_bf16(q3, kfB[3], sB, 0, 0, 0);
        __builtin_amdgcn_s_setprio(0);

        u32 mrA = __builtin_amdgcn_alignbit(mwA, mwA, hf * 4);  // rotr by 4*hf
        u32 mrB = __builtin_amdgcn_alignbit(mwB, mwB, hf * 4);

        float pA[16], pB[16];
#pragma unroll
        for (int r = 0; r < 16; ++r) {
            const int pos = (r & 3) + 8 * (r >> 2);
            float eA = __builtin_amdgcn_exp2f(sA[r]);
            float eB = __builtin_amdgcn_exp2f(sB[r]);
            pA[r] = ((mrA >> pos) & 1) ? eA : 0.f;
            pB[r] = ((mrB >> pos) & 1) ? eB : 0.f;
        }

        bf16x8 v00 = ldf(vb), v01 = ldf(vb + 512), v10 = ldf(vb + 1024), v11 = ldf(vb + 1536);

#pragma unroll
        for (int k2 = 0; k2 < 2; ++k2) {
            u32 aA  = pk2(pA[8 * k2 + 0], pA[8 * k2 + 1]);
            u32 bA  = pk2(pA[8 * k2 + 2], pA[8 * k2 + 3]);
            u32 cA  = pk2(pA[8 * k2 + 4], pA[8 * k2 + 5]);
            u32 dA  = pk2(pA[8 * k2 + 6], pA[8 * k2 + 7]);
            swap32(aA, cA);
            swap32(bA, dA);
            uint4 awA = {aA, bA, cA, dA};
            bf16x8 paA = __builtin_bit_cast(bf16x8, awA);
            u32 aB  = pk2(pB[8 * k2 + 0], pB[8 * k2 + 1]);
            u32 bB  = pk2(pB[8 * k2 + 2], pB[8 * k2 + 3]);
            u32 cB2 = pk2(pB[8 * k2 + 4], pB[8 * k2 + 5]);
            u32 dB  = pk2(pB[8 * k2 + 6], pB[8 * k2 + 7]);
            swap32(aB, cB2);
            swap32(bB, dB);
            uint4 awB = {aB, bB, cB2, dB};
            bf16x8 paB = __builtin_bit_cast(bf16x8, awB);
            bf16x8 v0 = (k2 == 0) ? v00 : v01;
            bf16x8 v1 = (k2 == 0) ? v10 : v11;
            __builtin_amdgcn_s_setprio(1);
            accA0 = __builtin_amdgcn_mfma_f32_32x32x16_bf16(paA, v0, accA0, 0, 0, 0);
            accB0 = __builtin_amdgcn_mfma_f32_32x32x16_bf16(paB, v0, accB0, 0, 0, 0);
            accA1 = __builtin_amdgcn_mfma_f32_32x32x16_bf16(paA, v1, accA1, 0, 0, 0);
            accB1 = __builtin_amdgcn_mfma_f32_32x32x16_bf16(paB, v1, accB1, 0, 0, 0);
            __builtin_amdgcn_s_setprio(0);
        }
    }

    // staged reduction per j-tile: 8 waves -> 4 -> final sum by all threads
    if (w >= 4) {
#pragma unroll
        for (int r = 0; r < 16; ++r) {
            int jl = (r & 3) + 8 * (r >> 2) + 4 * hf;
            red[0][w - 4][jl * 64 + l31] = accA0[r];
            red[0][w - 4][jl * 64 + 32 + l31] = accA1[r];
            red[1][w - 4][jl * 64 + l31] = accB0[r];
            red[1][w - 4][jl * 64 + 32 + l31] = accB1[r];
        }
    }
    __syncthreads();
    if (w < 4) {
#pragma unroll
        for (int r = 0; r < 16; ++r) {
            int jl = (r & 3) + 8 * (r >> 2) + 4 * hf;
            red[0][w][jl * 64 + l31] += accA0[r];
            red[0][w][jl * 64 + 32 + l31] += accA1[r];
            red[1][w][jl * 64 + l31] += accB0[r];
            red[1][w][jl * 64 + 32 + l31] += accB1[r];
        }
    }
    __syncthreads();
    {
        const int idx = threadIdx.x * 8;          // [0, 4096)
        const int g3 = idx >> 11, e = idx & 2047;
        float vv[8];
#pragma unroll
        for (int q = 0; q < 8; ++q) {
            int ee = e + q;
            float v = red[g3][0][ee] + red[g3][1][ee] + red[g3][2][ee] + red[g3][3][ee];
            vv[q] = v / (1.f + __expf(-v));
        }
        const int jl = e >> 6, hc = e & 63;
        float* dst = out + ((size_t)b * TT + (jt0 + g3) * 32 + jl) * HH + hc;
        *(float4*)dst = make_float4(vv[0], vv[1], vv[2], vv[3]);
        *(float4*)(dst + 4) = make_float4(vv[4], vv[5], vv[6], vv[7]);
    }
}

// ---------------------------------------------------------------------------
extern "C" void kernel_launch(void* const* d_in, const int* in_sizes, int n_in,
                              void* d_out, int out_size, void* d_ws, size_t ws_size,
                              hipStream_t stream) {
    const float* X  = (const float*)d_in[0];
    const int*  dag = (const int*)d_in[1];
    const float* Wk = (const float*)d_in[2];
    const float* Wq = (const float*)d_in[3];
    const float* Wv = (const float*)d_in[4];
    float* out = (float*)d_out;

    char* ws = (char*)d_ws;
    u16*   QF    = (u16*)ws;                                // 0..2 MB (A-frag, pre-scaled)
    u16*   KF    = (u16*)(ws + (2u << 20));                 // 2..4 MB (A-frag)
    u16*   VF    = (u16*)(ws + (4u << 20));                 // 4..6 MB (B-frag, unscaled)
    u16*   VF2   = (u16*)(ws + (6u << 20));                 // 6..8 MB (B-frag, scaled)
    u32*   bitsR = (u32*)(ws + (8u << 20));                 // 8..10 MB  [row][jt]
    u32*   bitsTT= (u32*)(ws + (10u << 20));                // 10..12 MB [it][j]
    u16*   WF    = (u16*)(ws + (12u << 20));                // 192 KB (B-frag W)

    wtr_kernel<<<24, 256, 0, stream>>>(Wq, Wk, Wv, WF);
    ppF_kernel<<<512 + 1024, 384, 0, stream>>>(X, WF, QF, KF, VF, dag, bitsR);
    transtats_kernel<<<1280, 512, 0, stream>>>(QF, KF, bitsR, VF, VF2, bitsTT);
    out_kernel<<<256, 512, 0, stream>>>(QF, KF, VF2, bitsTT, out);
}